// Round 19
// baseline (145.814 us; speedup 1.0000x reference)
//
#include <hip/hip_runtime.h>
#include <hip/hip_bf16.h>

#define NPATCH 15376       // 124*124 patches
#define NT     121         // B col-tiles (128 each)
#define ATILES 128         // A rows padded: 128*128 = 16384
#define TILE_SHORTS 12288  // 12*128*8 shorts per 128-row tile (24KB)
#define EPSA   1.30f       // acc-space margin; rigorous 2E ~= 1.16 (bf16 screen + f16 PM)
#define PMSTR  16384       // PMh row stride

typedef __attribute__((ext_vector_type(8))) __bf16 bf16x8;
typedef __attribute__((ext_vector_type(4))) float  f32x4;
typedef __attribute__((ext_vector_type(4))) _Float16 f16x4;
typedef float __attribute__((ext_vector_type(4), aligned(4))) f32x4u;  // 4B-aligned vec load

__device__ __forceinline__ unsigned short f2bf(float x) {
    __hip_bfloat16 h = __float2bfloat16(x);
    return *(unsigned short*)&h;
}
__device__ __forceinline__ float bf2f(unsigned short u) {
    __hip_bfloat16 h; *(unsigned short*)&h = u;
    return __bfloat162float(h);
}
__device__ __forceinline__ unsigned int fsort(float d) {   // monotone float->uint
    unsigned int b = __builtin_bit_cast(unsigned int, d);
    return (b & 0x80000000u) ? ~b : (b | 0x80000000u);
}

// ---------- squared norms (vectorized, fma order identical to scalar version) + WLn init
__global__ void sqnorm2(const float* __restrict__ crop, const float* __restrict__ orig,
                        float* __restrict__ X2, float* __restrict__ Y2,
                        unsigned int* __restrict__ WLn) {
    int p = blockIdx.x * 256 + threadIdx.x;
    if (p == 0) *WLn = 0;
    const float* img;
    float* dst;
    int q;
    if (p < NPATCH) { img = orig; dst = Y2; q = p; }
    else {
        q = p - NPATCH;
        if (q >= NPATCH) return;
        img = crop; dst = X2;
    }
    int pr = q / 124, pc = q - pr * 124;
    const float* base = img + pr * 128 + pc;
    float s = 0.f;
    #pragma unroll
    for (int ch = 0; ch < 3; ++ch)
        #pragma unroll
        for (int di = 0; di < 5; ++di) {
            const int o = ch * 16384 + di * 128;
            const f32x4u v = *(const f32x4u*)(base + o);
            const float  w = base[o + 4];
            s = fmaf(v.x, v.x, s);
            s = fmaf(v.y, v.y, s);
            s = fmaf(v.z, v.z, s);
            s = fmaf(v.w, v.w, s);
            s = fmaf(w,  w,  s);
        }
    dst[q] = s;
}

// ---------- pack both matrices: tile-major [tile][kslot12][row128][8] bf16.
// features 0..74 = bf16(patch); slot 75/76: A -> -0.5,-0.5 ; B -> Y2hi,Y2lo; rest 0.
__global__ void pack2(const float* __restrict__ crop, const float* __restrict__ orig,
                      unsigned short* __restrict__ Abig, unsigned short* __restrict__ Bbig,
                      const float* __restrict__ Y2) {
    int cid = blockIdx.x * 256 + threadIdx.x;
    const float* img;
    unsigned short* dst;
    bool isA;
    if (cid < ATILES * 1536) { img = crop; dst = Abig; isA = true; }
    else { cid -= ATILES * 1536; img = orig; dst = Bbig; isA = false; }
    int t = cid / 1536, rem = cid - t * 1536;
    int s = rem >> 7, r = rem & 127;
    int row = t * 128 + r;
    unsigned short ch8[8];
    #pragma unroll
    for (int e = 0; e < 8; ++e) {
        int k = s * 8 + e;
        unsigned short v = 0;
        if (k < 75) {
            if (row < NPATCH) {
                int c = k / 25, rem2 = k - c * 25;
                int di = rem2 / 5, dj = rem2 - di * 5;
                int pr = row / 124, pc = row - pr * 124;
                v = f2bf(img[c * 16384 + (pr + di) * 128 + (pc + dj)]);
            }
        } else if (k < 77) {
            if (isA) v = f2bf(-0.5f);
            else {
                float yv = (row < NPATCH) ? Y2[row] : 3.0e38f;   // pad synthesized
                unsigned short hi = f2bf(yv);
                v = (k == 75) ? hi : f2bf(yv - bf2f(hi));
            }
        }
        ch8[e] = v;
    }
    *(ulonglong2*)(dst + (size_t)cid * 8) = *(ulonglong2*)ch8;
}

// ---------- MFMA screen, barrier-free, 16 chunks (8192 waves): B streamed L2->regs
__global__ __launch_bounds__(256, 2)
void dist_mfma6(const unsigned short* __restrict__ A, const unsigned short* __restrict__ B,
                _Float16* __restrict__ PMh) {
    __shared__ _Float16 stash[4][8][64];   // 4 KB, wave-private slices: no barriers

    const int tid = threadIdx.x, lane = tid & 63, wid = tid >> 6;
    const int l15 = lane & 15, l4 = lane >> 4;

    const int g = blockIdx.x * 4 + wid;          // 0..8191
    const int cg = g & 1;
    const int cgrp = (g >> 1) & 15;
    const int rowgroup = g >> 5;                 // 0..255 (64 rows each)
    const int t0 = (cgrp < 9) ? cgrp * 8 : 72 + (cgrp - 9) * 7;
    const int nt = (cgrp < 9) ? 8 : 7;           // 9*8 + 7*7 = 121

    bf16x8 a[4][3];
    {
        const int atile = rowgroup >> 1, rbase = (rowgroup & 1) * 64;
        const unsigned short* Ab =
            A + ((size_t)atile * 12 + l4) * 1024 + (size_t)(rbase + l15) * 8;
        #pragma unroll
        for (int mi = 0; mi < 4; ++mi)
            #pragma unroll
            for (int k3 = 0; k3 < 3; ++k3)
                a[mi][k3] = *(const bf16x8*)(Ab + k3 * 4096 + mi * 128);
    }

    const size_t cgofs = (size_t)cg * 512 + (size_t)l15 * 8;
    bf16x8 b0[12], b1[12];

#define BLOAD(bank, tile)                                                         \
    {                                                                             \
        const unsigned short* _B = B + ((size_t)(tile) * 12 + l4) * 1024 + cgofs; \
        _Pragma("unroll")                                                         \
        for (int _ni = 0; _ni < 4; ++_ni)                                         \
            _Pragma("unroll")                                                     \
            for (int _k3 = 0; _k3 < 3; ++_k3)                                     \
                bank[_ni * 3 + _k3] = *(const bf16x8*)(_B + _k3 * 4096 + _ni * 128); \
    }

#define COMPUTE(bank, it)                                                         \
    {                                                                             \
        f32x4 acc[4][4];                                                          \
        _Pragma("unroll")                                                         \
        for (int _k3 = 0; _k3 < 3; ++_k3)                                         \
            _Pragma("unroll")                                                     \
            for (int _mi = 0; _mi < 4; ++_mi)                                     \
                _Pragma("unroll")                                                 \
                for (int _ni = 0; _ni < 4; ++_ni)                                 \
                    acc[_mi][_ni] = __builtin_amdgcn_mfma_f32_16x16x32_bf16(      \
                        bank[_ni * 3 + _k3], a[_mi][_k3],                         \
                        (_k3 == 0) ? (f32x4){0.f, 0.f, 0.f, 0.f} : acc[_mi][_ni], \
                        0, 0, 0);                                                 \
        _Pragma("unroll")                                                         \
        for (int _mi = 0; _mi < 4; ++_mi) {                                       \
            float _m = acc[_mi][0][0];                                            \
            _Pragma("unroll")                                                     \
            for (int _ni = 0; _ni < 4; ++_ni)                                     \
                _Pragma("unroll")                                                 \
                for (int _j = 0; _j < 4; ++_j)                                    \
                    if (_ni + _j) _m = fmaxf(_m, acc[_mi][_ni][_j]);              \
            _m = fmaxf(_m, __shfl_xor(_m, 16));                                   \
            _m = fmaxf(_m, __shfl_xor(_m, 32));                                   \
            if (l4 == 0) stash[wid][it][_mi * 16 + l15] = (_Float16)_m;           \
        }                                                                         \
    }

    BLOAD(b0, t0);
    int it = 0;
    while (true) {
        if (it + 1 < nt) BLOAD(b1, t0 + it + 1);
        COMPUTE(b0, it);
        ++it;
        if (it >= nt) break;
        if (it + 1 < nt) BLOAD(b0, t0 + it + 1);
        COMPUTE(b1, it);
        ++it;
        if (it >= nt) break;
    }
#undef BLOAD
#undef COMPUTE

    for (int i2 = 0; i2 < nt; ++i2)
        PMh[(size_t)((t0 + i2) * 2 + cg) * PMSTR + rowgroup * 64 + lane] = stash[wid][i2][lane];
}

// ---------- flag: single-wave blocks, zero barriers, shfl-scan, one atomic per wave
__global__ __launch_bounds__(64)
void flag_kernel(const _Float16* __restrict__ PMh,
                 unsigned int* __restrict__ WL, unsigned int* __restrict__ WLn,
                 unsigned long long* __restrict__ RES) {
    __shared__ _Float16 cachev[NT][64];   // 15.5 KB; per-thread-private columns

    const int lane = threadIdx.x;
    const int r = blockIdx.x * 64 + lane;
    const int rr = (r < NPATCH) ? r : (NPATCH - 1);

    float mt = -3.4e38f;
    for (int t = 0; t < NT; ++t) {
        float v0 = (float)PMh[(size_t)(2 * t) * PMSTR + rr];
        float v1 = (float)PMh[(size_t)(2 * t + 1) * PMSTR + rr];
        float v = fmaxf(v0, v1);
        cachev[t][lane] = (_Float16)v;     // exact: max of two f16 is an f16
        mt = fmaxf(mt, v);
    }
    if (r < NPATCH) RES[r] = 0xFFFFFFFFFFFFFFFFULL;
    const float thr = mt - EPSA;

    int cnt = 0;
    if (r < NPATCH)
        for (int t = 0; t < NT; ++t)
            cnt += ((float)cachev[t][lane] >= thr) ? 1 : 0;

    int sc = cnt;                          // wave inclusive scan (no barriers)
    #pragma unroll
    for (int off = 1; off < 64; off <<= 1) {
        int v = __shfl_up(sc, off);
        if (lane >= off) sc += v;
    }
    unsigned int total = (unsigned int)__shfl(sc, 63);
    unsigned int base = 0;
    if (lane == 63) base = atomicAdd(WLn, total);
    base = __shfl(base, 63);

    if (r < NPATCH) {
        unsigned int w = base + (unsigned int)(sc - cnt);
        for (int t = 0; t < NT; ++t)
            if ((float)cachev[t][lane] >= thr)
                WL[w++] = ((unsigned int)r << 7) | (unsigned int)t;
    }
}

// ---------- repair: FOUR items per wave (8 independent chains), branch-free, atomicMin
__global__ __launch_bounds__(256)
void repair_items(const float* __restrict__ crop, const float* __restrict__ orig,
                  const float* __restrict__ X2, const float* __restrict__ Y2,
                  const unsigned int* __restrict__ WL, const unsigned int* __restrict__ WLn,
                  unsigned long long* __restrict__ RES) {
    const int lane = threadIdx.x & 63;
    const unsigned int gw = (blockIdx.x * 256 + threadIdx.x) >> 6;
    const unsigned int nw = (gridDim.x * 256) >> 6;
    const unsigned int n = *WLn;

    for (unsigned int p = gw; 4 * p < n; p += nw) {
        int r4[4], tl4[4];
        const float* xb4[4];
        float x24[4];
        #pragma unroll
        for (int k = 0; k < 4; ++k) {
            unsigned int ii = 4 * p + k;
            ii = (ii < n) ? ii : (n - 1);                        // dup tail benign
            const unsigned int item = __builtin_amdgcn_readfirstlane(WL[ii]);
            r4[k] = (int)(item >> 7);
            tl4[k] = (int)(item & 127u);
            const int pr = r4[k] / 124, pc = r4[k] - pr * 124;
            xb4[k] = crop + pr * 128 + pc;                       // wave-uniform -> s_loads
            x24[k] = X2[r4[k]];
        }

        int jj[4][2];
        const float* yy[4][2];
        float dd[4][2];
        #pragma unroll
        for (int k = 0; k < 4; ++k)
            #pragma unroll
            for (int h = 0; h < 2; ++h) {
                jj[k][h] = min(tl4[k] * 128 + h * 64 + lane, NPATCH - 1);  // clamp: dup pair
                yy[k][h] = orig + (jj[k][h] / 124) * 128 + (jj[k][h] % 124);
                dd[k][h] = 0.f;
            }

        #pragma unroll
        for (int ch = 0; ch < 3; ++ch) {
            #pragma unroll
            for (int di = 0; di < 5; ++di) {
                const int o = ch * 16384 + di * 128;
                f32x4u v[4][2];
                float  w[4][2];
                #pragma unroll
                for (int k = 0; k < 4; ++k)
                    #pragma unroll
                    for (int h = 0; h < 2; ++h) {
                        v[k][h] = *(const f32x4u*)(yy[k][h] + o);
                        w[k][h] = yy[k][h][o + 4];
                    }
                float xt[4][5];
                #pragma unroll
                for (int k = 0; k < 4; ++k)
                    #pragma unroll
                    for (int tp = 0; tp < 5; ++tp)
                        xt[k][tp] = xb4[k][o + tp];
                // per-chain fma order identical to r4-r15 (taps 0,1,2,3,4)
                #pragma unroll
                for (int tp = 0; tp < 4; ++tp)
                    #pragma unroll
                    for (int k = 0; k < 4; ++k)
                        #pragma unroll
                        for (int h = 0; h < 2; ++h)
                            dd[k][h] = fmaf(xt[k][tp], v[k][h][tp], dd[k][h]);
                #pragma unroll
                for (int k = 0; k < 4; ++k)
                    #pragma unroll
                    for (int h = 0; h < 2; ++h)
                        dd[k][h] = fmaf(xt[k][4], w[k][h], dd[k][h]);
            }
        }

        float bd[4];
        int   bj[4];
        #pragma unroll
        for (int k = 0; k < 4; ++k) {
            const float e0 = fmaf(-2.f, dd[k][0], x24[k]) + Y2[jj[k][0]];
            const float e1 = fmaf(-2.f, dd[k][1], x24[k]) + Y2[jj[k][1]];
            const bool s = (e1 < e0) || (e1 == e0 && jj[k][1] < jj[k][0]);
            bd[k] = s ? e1 : e0;
            bj[k] = s ? jj[k][1] : jj[k][0];
        }

        float dm[4] = {bd[0], bd[1], bd[2], bd[3]};
        #pragma unroll
        for (int off = 1; off < 64; off <<= 1)
            #pragma unroll
            for (int k = 0; k < 4; ++k)
                dm[k] = fminf(dm[k], __shfl_xor(dm[k], off));
        int jc[4];
        #pragma unroll
        for (int k = 0; k < 4; ++k)
            jc[k] = (bd[k] == dm[k]) ? bj[k] : 0x7fffffff;
        #pragma unroll
        for (int off = 1; off < 64; off <<= 1)
            #pragma unroll
            for (int k = 0; k < 4; ++k)
                jc[k] = min(jc[k], __shfl_xor(jc[k], off));

        if (lane == 0) {
            #pragma unroll
            for (int k = 0; k < 4; ++k)
                atomicMin(RES + r4[k],
                          (((unsigned long long)fsort(dm[k])) << 32) | (unsigned int)jc[k]);
        }
    }
}

// ---------- finalize: unpack RES -> out idx + rsum
__global__ void finalize_kernel(const unsigned long long* __restrict__ RES,
                                float* __restrict__ out, float* __restrict__ rsum) {
    int r = blockIdx.x * 256 + threadIdx.x;
    if (r >= NPATCH) return;
    unsigned long long v = RES[r];
    unsigned int j = (unsigned int)v;
    unsigned int u = (unsigned int)(v >> 32);
    unsigned int b = (u & 0x80000000u) ? (u ^ 0x80000000u) : ~u;
    out[1 + r] = (float)j;
    rsum[r] = __builtin_bit_cast(float, b);
}

// ---------- deterministic final loss
__global__ void loss_final(const float* __restrict__ rsum, float* __restrict__ out) {
    __shared__ float s[256];
    float acc = 0.f;
    for (int i = threadIdx.x; i < NPATCH; i += 256) acc += rsum[i];
    s[threadIdx.x] = acc;
    __syncthreads();
    for (int st = 128; st > 0; st >>= 1) {
        if (threadIdx.x < st) s[threadIdx.x] += s[threadIdx.x + st];
        __syncthreads();
    }
    if (threadIdx.x == 0) out[0] = s[0] / (float)NPATCH;
}

extern "C" void kernel_launch(void* const* d_in, const int* in_sizes, int n_in,
                              void* d_out, int out_size, void* d_ws, size_t ws_size,
                              hipStream_t stream) {
    const float* crop = (const float*)d_in[0];
    const float* orig = (const float*)d_in[1];
    float* out = (float*)d_out;

    unsigned short* Abig = (unsigned short*)d_ws;                     // 3.15 MB
    unsigned short* Bbig = Abig + (size_t)ATILES * TILE_SHORTS;       // 2.97 MB
    _Float16* PMh = (_Float16*)(Bbig + (size_t)NT * TILE_SHORTS);     // 242*16384*2 = 7.93 MB
    float* X2 = (float*)(PMh + (size_t)242 * PMSTR);                  // 61.5 KB
    float* Y2 = X2 + NPATCH;                                          // 61.5 KB
    unsigned long long* RES = (unsigned long long*)(Y2 + NPATCH);     // 123 KB
    float* RS = (float*)(RES + NPATCH);                               // 61.5 KB
    unsigned int* WLn = (unsigned int*)(RS + NPATCH);                 // 64 B
    unsigned int* WL = WLn + 16;                                      // 7.44 MB (worst case)
                                                                      // total ~= 21.8 MB

    sqnorm2<<<(2 * NPATCH + 255) / 256, 256, 0, stream>>>(crop, orig, X2, Y2, WLn);
    pack2<<<(ATILES + NT) * 6, 256, 0, stream>>>(crop, orig, Abig, Bbig, Y2);
    dist_mfma6<<<2048, 256, 0, stream>>>(Abig, Bbig, PMh);
    flag_kernel<<<(NPATCH + 63) / 64, 64, 0, stream>>>(PMh, WL, WLn, RES);
    repair_items<<<2048, 256, 0, stream>>>(crop, orig, X2, Y2, WL, WLn, RES);
    finalize_kernel<<<(NPATCH + 255) / 256, 256, 0, stream>>>(RES, out, RS);
    loss_final<<<1, 256, 0, stream>>>(RS, out);
}